// Round 1
// baseline (171.805 us; speedup 1.0000x reference)
//
#include <hip/hip_runtime.h>

// WindowAttention fused kernel, MI355X (gfx950).
// B=4096 windows, N=49 (pad 64), C=128, H=4 heads, d=32.
// Strategy: bf16 MFMA (16x16x32) for all four GEMMs, fp32 accumulate,
// fp32 softmax. One block per window, wave w == head w for the attn core.

typedef __attribute__((ext_vector_type(8))) short bf16x8;   // 8 bf16 = 4 VGPRs
typedef __attribute__((ext_vector_type(4))) float f32x4;    // MFMA C/D

#define MFMA16(a, b, c) __builtin_amdgcn_mfma_f32_16x16x32_bf16((a), (b), (c), 0, 0, 0)

__device__ __forceinline__ unsigned short f2bf(float f) {
  unsigned int u = __float_as_uint(f);
  u += 0x7fffu + ((u >> 16) & 1u);          // round-to-nearest-even
  return (unsigned short)(u >> 16);
}

// ---- workspace layout (bytes) ----
// qkvT : bf16 [384][128]  (col-major W, q-scale folded into first 128 rows)
// projT: bf16 [128][128]  (col-major W)
// biasF: f32  [4][49][49] (pre-gathered relative position bias)
// bsc  : f32  [384]       (qkv_b, q part scaled)
#define OFF_QKVT  0u
#define OFF_PROJT 98304u
#define OFF_BIAS  131072u
#define OFF_BSC   169488u

__global__ void prep_kernel(const float* __restrict__ qkv_w,
                            const float* __restrict__ qkv_b,
                            const float* __restrict__ proj_w,
                            const float* __restrict__ bias_table,
                            const int*   __restrict__ rel_index,
                            char* __restrict__ ws) {
  const float scale = 0.1767766952966369f;  // 32^-0.5
  int idx = blockIdx.x * 256 + threadIdx.x;
  if (idx < 49152) {                         // qkvT[n][k] = qkv_w[k][n] (*scale for q cols)
    int n = idx >> 7, k = idx & 127;
    float v = qkv_w[k * 384 + n];
    if (n < 128) v *= scale;
    ((unsigned short*)(ws + OFF_QKVT))[idx] = f2bf(v);
  } else if (idx < 65536) {                  // projT[n][k] = proj_w[k][n]
    int j = idx - 49152;
    int n = j >> 7, k = j & 127;
    ((unsigned short*)(ws + OFF_PROJT))[j] = f2bf(proj_w[k * 128 + n]);
  } else if (idx < 65536 + 9604) {           // biasF[h][r][c] = table[rel_index[r][c]][h]
    int j = idx - 65536;
    int h = j / 2401, rem = j % 2401;
    ((float*)(ws + OFF_BIAS))[j] = bias_table[rel_index[rem] * 4 + h];
  } else if (idx < 65536 + 9604 + 384) {     // scaled qkv bias
    int j = idx - (65536 + 9604);
    float v = qkv_b[j];
    if (j < 128) v *= scale;
    ((float*)(ws + OFF_BSC))[j] = v;
  }
}

// LDS map (65536 B total):
//   [0, 16384)            xs: bf16 [64 rows][128 cols], swizzled; reused as `mid` after PV
//   [16384 + h*12288)     per-head block:
//       +0     qk[h]: bf16 [64 rows][64 cols] (cols 0-31 = q, 32-63 = k); reused as P[h]
//       +8192  vT[h]: bf16 [32 rows(dcol)][64 cols(key)]
// swizzle: byteoff_in_row ^= (row&7)<<4  (all regions have rowBytes 128 or 256)

__global__ __launch_bounds__(256, 2)
void win_attn_kernel(const float* __restrict__ x,
                     const float* __restrict__ mask,
                     const float* __restrict__ proj_b,
                     const char*  __restrict__ ws,
                     float* __restrict__ out) {
  __shared__ __align__(16) char smem[65536];
  const int b    = blockIdx.x;
  const int tid  = threadIdx.x;
  const int w    = tid >> 6;        // wave id == head id
  const int lane = tid & 63;
  const int l16  = lane & 15;
  const int lg   = lane >> 4;

  const unsigned short* qkvT  = (const unsigned short*)(ws + OFF_QKVT);
  const unsigned short* projT = (const unsigned short*)(ws + OFF_PROJT);
  const float* biasF = (const float*)(ws + OFF_BIAS);
  const float* bsc   = (const float*)(ws + OFF_BSC);

  const unsigned qkb = 16384u + (unsigned)w * 12288u;
  const unsigned vtb = qkb + 8192u;

  // ================= stage x -> xs (bf16, swizzled, rows 49..63 zeroed) =================
  {
    const float* xb = x + (size_t)b * 6272;
#pragma unroll
    for (int it = 0; it < 7; ++it) {
      int i = tid + it * 256;
      if (i < 1568) {
        int row = i >> 5, c4 = i & 31;
        float4 v = *(const float4*)(xb + row * 128 + c4 * 4);
        unsigned lo = (unsigned)f2bf(v.x) | ((unsigned)f2bf(v.y) << 16);
        unsigned hi = (unsigned)f2bf(v.z) | ((unsigned)f2bf(v.w) << 16);
        unsigned off = (unsigned)row * 256u + (((unsigned)c4 * 8u) ^ (((unsigned)row & 7u) << 4));
        *(uint2*)(smem + off) = make_uint2(lo, hi);
      }
    }
#pragma unroll
    for (int it = 0; it < 2; ++it) {
      int i = tid + it * 256;
      if (i < 480) {
        int row = 49 + (i >> 5), c4 = i & 31;
        unsigned off = (unsigned)row * 256u + (((unsigned)c4 * 8u) ^ (((unsigned)row & 7u) << 4));
        *(uint2*)(smem + off) = make_uint2(0u, 0u);
      }
    }
  }
  __syncthreads();

  // ================= GEMM1: QKV[64x384] = xs[64x128] @ W + b =================
  // wave w owns output cols [96w, 96w+96): 6 n-tiles x 4 m-tiles x 4 k-steps.
  {
    const int cb = 96 * w;
    f32x4 acc[4][6];
#pragma unroll
    for (int t = 0; t < 6; ++t) {
      float bi = bsc[cb + 16 * t + l16];
#pragma unroll
      for (int mt = 0; mt < 4; ++mt) acc[mt][t] = (f32x4){bi, bi, bi, bi};
    }
#pragma unroll
    for (int ks = 0; ks < 4; ++ks) {
      bf16x8 a[4];
#pragma unroll
      for (int mt = 0; mt < 4; ++mt) {
        int r = 16 * mt + l16;
        unsigned off = (unsigned)r * 256u +
                       (((unsigned)(64 * ks + 16 * lg)) ^ (((unsigned)r & 7u) << 4));
        a[mt] = *(const bf16x8*)(smem + off);
      }
#pragma unroll
      for (int t = 0; t < 6; ++t) {
        bf16x8 bfr = *(const bf16x8*)(qkvT + (cb + 16 * t + l16) * 128 + 32 * ks + 8 * lg);
#pragma unroll
        for (int mt = 0; mt < 4; ++mt) acc[mt][t] = MFMA16(a[mt], bfr, acc[mt][t]);
      }
    }
    // scatter to q/k (row-major) and vT (transposed), bf16, swizzled
#pragma unroll
    for (int t = 0; t < 6; ++t) {
      const int c0 = cb + 16 * t;  // wave-uniform, 16-aligned
#pragma unroll
      for (int mt = 0; mt < 4; ++mt) {
#pragma unroll
        for (int i = 0; i < 4; ++i) {
          int r = 16 * mt + 4 * lg + i;
          unsigned short bv = f2bf(acc[mt][t][i]);
          unsigned off;
          if (c0 < 256) {  // q or k
            int hh = (c0 & 127) >> 5;
            int lc = ((c0 & 31) + l16) + ((c0 < 128) ? 0 : 32);
            off = 16384u + (unsigned)hh * 12288u + (unsigned)r * 128u +
                  (((unsigned)(lc * 2)) ^ (((unsigned)r & 7u) << 4));
          } else {          // v, stored transposed [dcol][key]
            int hh = (c0 - 256) >> 5;
            int dc = (c0 & 31) + l16;
            off = 16384u + (unsigned)hh * 12288u + 8192u + (unsigned)dc * 128u +
                  (((unsigned)(r * 2)) ^ (((unsigned)dc & 7u) << 4));
          }
          *(unsigned short*)(smem + off) = bv;
        }
      }
    }
  }
  __syncthreads();

  // ================= attention core (wave w == head w) =================
  float rs[4][4];  // per-(mtile, reg) reciprocal row sums, survive to PV epilogue
  {
    bf16x8 qf[4], kf[4];
#pragma unroll
    for (int mt = 0; mt < 4; ++mt) {
      int r = 16 * mt + l16;
      qf[mt] = *(const bf16x8*)(smem + qkb + (unsigned)r * 128u +
                                (((unsigned)(16 * lg)) ^ (((unsigned)r & 7u) << 4)));
    }
#pragma unroll
    for (int nt = 0; nt < 4; ++nt) {
      int r = 16 * nt + l16;
      kf[nt] = *(const bf16x8*)(smem + qkb + (unsigned)r * 128u +
                                (((unsigned)(64 + 16 * lg)) ^ (((unsigned)r & 7u) << 4)));
    }
    f32x4 p[4][4];
#pragma unroll
    for (int mt = 0; mt < 4; ++mt)
#pragma unroll
      for (int nt = 0; nt < 4; ++nt) p[mt][nt] = (f32x4){0.f, 0.f, 0.f, 0.f};
#pragma unroll
    for (int mt = 0; mt < 4; ++mt)
#pragma unroll
      for (int nt = 0; nt < 4; ++nt) p[mt][nt] = MFMA16(qf[mt], kf[nt], p[mt][nt]);

    // bias + mask + bounds masking
    const float* mb = mask + (size_t)b * 2401;
    const float* bh = biasF + w * 2401;
#pragma unroll
    for (int mt = 0; mt < 4; ++mt)
#pragma unroll
      for (int nt = 0; nt < 4; ++nt)
#pragma unroll
        for (int i = 0; i < 4; ++i) {
          int r = 16 * mt + 4 * lg + i;
          int c = 16 * nt + l16;
          float v = p[mt][nt][i];
          if (r < 49 && c < 49) v += bh[r * 49 + c] + mb[r * 49 + c];
          else v = -1e30f;
          p[mt][nt][i] = v;
        }

    // row softmax (rows live across 16 lanes x 4 ntiles)
#pragma unroll
    for (int mt = 0; mt < 4; ++mt)
#pragma unroll
      for (int i = 0; i < 4; ++i) {
        float m = fmaxf(fmaxf(p[mt][0][i], p[mt][1][i]), fmaxf(p[mt][2][i], p[mt][3][i]));
#pragma unroll
        for (int d = 1; d < 16; d <<= 1) m = fmaxf(m, __shfl_xor(m, d));
        float s = 0.f;
#pragma unroll
        for (int nt = 0; nt < 4; ++nt) {
          float e = __expf(p[mt][nt][i] - m);
          p[mt][nt][i] = e;
          s += e;
        }
#pragma unroll
        for (int d = 1; d < 16; d <<= 1) s += __shfl_xor(s, d);
        rs[mt][i] = 1.0f / s;
      }

    // write P (bf16) over the dead q/k region of this head (wave-private)
#pragma unroll
    for (int mt = 0; mt < 4; ++mt)
#pragma unroll
      for (int nt = 0; nt < 4; ++nt)
#pragma unroll
        for (int i = 0; i < 4; ++i) {
          int r = 16 * mt + 4 * lg + i;
          int c = 16 * nt + l16;
          unsigned off = qkb + (unsigned)r * 128u +
                         (((unsigned)(c * 2)) ^ (((unsigned)r & 7u) << 4));
          *(unsigned short*)(smem + off) = f2bf(p[mt][nt][i]);
        }
  }
  __syncthreads();

  // ================= PV: O[64x32] = P[64x64] @ V[64x32], then -> mid =================
  {
    f32x4 o[4][2];
#pragma unroll
    for (int mt = 0; mt < 4; ++mt)
#pragma unroll
      for (int nt = 0; nt < 2; ++nt) o[mt][nt] = (f32x4){0.f, 0.f, 0.f, 0.f};
#pragma unroll
    for (int ks = 0; ks < 2; ++ks) {
      bf16x8 pa[4], vb[2];
#pragma unroll
      for (int mt = 0; mt < 4; ++mt) {
        int r = 16 * mt + l16;
        pa[mt] = *(const bf16x8*)(smem + qkb + (unsigned)r * 128u +
                                  (((unsigned)(64 * ks + 16 * lg)) ^ (((unsigned)r & 7u) << 4)));
      }
#pragma unroll
      for (int nt = 0; nt < 2; ++nt) {
        int r = 16 * nt + l16;  // dcol
        vb[nt] = *(const bf16x8*)(smem + vtb + (unsigned)r * 128u +
                                  (((unsigned)(64 * ks + 16 * lg)) ^ (((unsigned)r & 7u) << 4)));
      }
#pragma unroll
      for (int mt = 0; mt < 4; ++mt)
#pragma unroll
        for (int nt = 0; nt < 2; ++nt) o[mt][nt] = MFMA16(pa[mt], vb[nt], o[mt][nt]);
    }
    // normalize rows and write mid[row][32*w + dcol] into xs region (bf16, swizzled)
#pragma unroll
    for (int mt = 0; mt < 4; ++mt)
#pragma unroll
      for (int nt = 0; nt < 2; ++nt)
#pragma unroll
        for (int i = 0; i < 4; ++i) {
          int r = 16 * mt + 4 * lg + i;
          int c = 32 * w + 16 * nt + l16;
          float val = o[mt][nt][i] * rs[mt][i];
          unsigned off = (unsigned)r * 256u +
                         (((unsigned)(c * 2)) ^ (((unsigned)r & 7u) << 4));
          *(unsigned short*)(smem + off) = f2bf(val);
        }
  }
  __syncthreads();

  // ================= GEMM2: out[64x128] = mid[64x128] @ projW + proj_b =================
  // wave w owns output cols [32w, 32w+32): 2 n-tiles x 4 m-tiles x 4 k-steps.
  {
    f32x4 c_[4][2];
#pragma unroll
    for (int nt = 0; nt < 2; ++nt) {
      float pb = proj_b[32 * w + 16 * nt + l16];
#pragma unroll
      for (int mt = 0; mt < 4; ++mt) c_[mt][nt] = (f32x4){pb, pb, pb, pb};
    }
#pragma unroll
    for (int ks = 0; ks < 4; ++ks) {
      bf16x8 a2[4];
#pragma unroll
      for (int mt = 0; mt < 4; ++mt) {
        int r = 16 * mt + l16;
        unsigned off = (unsigned)r * 256u +
                       (((unsigned)(64 * ks + 16 * lg)) ^ (((unsigned)r & 7u) << 4));
        a2[mt] = *(const bf16x8*)(smem + off);
      }
#pragma unroll
      for (int nt = 0; nt < 2; ++nt) {
        bf16x8 b2 = *(const bf16x8*)(projT + (32 * w + 16 * nt + l16) * 128 + 32 * ks + 8 * lg);
#pragma unroll
        for (int mt = 0; mt < 4; ++mt) c_[mt][nt] = MFMA16(a2[mt], b2, c_[mt][nt]);
      }
    }
    float* ob = out + (size_t)b * 6272;
#pragma unroll
    for (int mt = 0; mt < 4; ++mt)
#pragma unroll
      for (int nt = 0; nt < 2; ++nt)
#pragma unroll
        for (int i = 0; i < 4; ++i) {
          int r = 16 * mt + 4 * lg + i;
          if (r < 49) ob[r * 128 + 32 * w + 16 * nt + l16] = c_[mt][nt][i];
        }
  }
}

extern "C" void kernel_launch(void* const* d_in, const int* in_sizes, int n_in,
                              void* d_out, int out_size, void* d_ws, size_t ws_size,
                              hipStream_t stream) {
  const float* x          = (const float*)d_in[0];
  const float* mask       = (const float*)d_in[1];
  const float* qkv_w      = (const float*)d_in[2];
  const float* qkv_b      = (const float*)d_in[3];
  const float* proj_w     = (const float*)d_in[4];
  const float* proj_b     = (const float*)d_in[5];
  const float* bias_table = (const float*)d_in[6];
  const int*   rel_index  = (const int*)d_in[7];
  char* ws = (char*)d_ws;

  prep_kernel<<<296, 256, 0, stream>>>(qkv_w, qkv_b, proj_w, bias_table, rel_index, ws);
  win_attn_kernel<<<4096, 256, 0, stream>>>(x, mask, proj_b, ws, (float*)d_out);
}

// Round 2
// 170.873 us; speedup vs baseline: 1.0055x; 1.0055x over previous
//
#include <hip/hip_runtime.h>

// WindowAttention fused kernel, MI355X (gfx950).  R1: wave-private dataflow.
// B=4096 windows, N=49 (pad 64), C=128, H=4 heads, d=32.
// One block per window; wave w owns head w end-to-end (q,k,v,P private).
// Single __syncthreads (before proj GEMM). LDS 48KB -> 3 blocks/CU.

typedef __attribute__((ext_vector_type(8))) short bf16x8;   // 8 bf16 = 4 VGPRs
typedef __attribute__((ext_vector_type(4))) float f32x4;    // MFMA C/D
typedef __attribute__((ext_vector_type(4))) unsigned int u32x4;

#define MFMA16(a, b, c) __builtin_amdgcn_mfma_f32_16x16x32_bf16((a), (b), (c), 0, 0, 0)

// pack two fp32 -> two bf16 (round-half-up) in one u32: 2 adds + 1 v_perm
__device__ __forceinline__ unsigned pk2(float lo, float hi) {
  return __builtin_amdgcn_perm(__float_as_uint(hi) + 0x8000u,
                               __float_as_uint(lo) + 0x8000u, 0x07060302u);
}
__device__ __forceinline__ unsigned short bf1(float v) {
  return (unsigned short)((__float_as_uint(v) + 0x8000u) >> 16);
}

// ---- workspace layout (bytes) ----
#define OFF_QKVT  0u        // bf16 [384][128] col-major W, q-scale folded
#define OFF_PROJT 98304u    // bf16 [128][128] col-major W
#define OFF_BIAS  131072u   // f32  [4][49][49] gathered rel-pos bias
#define OFF_BSC   169488u   // f32  [384] qkv_b (q part scaled)

__global__ void prep_kernel(const float* __restrict__ qkv_w,
                            const float* __restrict__ qkv_b,
                            const float* __restrict__ proj_w,
                            const float* __restrict__ bias_table,
                            const int*   __restrict__ rel_index,
                            char* __restrict__ ws) {
  const float scale = 0.1767766952966369f;  // 32^-0.5
  int idx = blockIdx.x * 256 + threadIdx.x;
  if (idx < 49152) {
    int n = idx >> 7, k = idx & 127;
    float v = qkv_w[k * 384 + n];
    if (n < 128) v *= scale;
    ((unsigned short*)(ws + OFF_QKVT))[idx] = bf1(v);
  } else if (idx < 65536) {
    int j = idx - 49152;
    int n = j >> 7, k = j & 127;
    ((unsigned short*)(ws + OFF_PROJT))[j] = bf1(proj_w[k * 128 + n]);
  } else if (idx < 65536 + 9604) {
    int j = idx - 65536;
    int h = j / 2401, rem = j % 2401;
    ((float*)(ws + OFF_BIAS))[j] = bias_table[rel_index[rem] * 4 + h];
  } else if (idx < 65536 + 9604 + 384) {
    int j = idx - (65536 + 9604);
    float v = qkv_b[j];
    if (j < 128) v *= scale;
    ((float*)(ws + OFF_BSC))[j] = v;
  }
}

// LDS per head h at HB=h*12288 (total 48 KB):
//   KO=HB+0    : K  bf16 [64 tok][32 d], 64B rows, byte = tok*64 + (2d ^ (((tok>>2)&3)<<4))
//   QO=HB+4096 : Q  bf16 [64 tok][32 d], same swizzle
//   VT=HB+8192 : Vt bf16 [32 d][64 key], 128B rows, byte = d*128 + (2key ^ ((d&7)<<4))
//   PO=HB+0    : P  bf16 [64 q][64 key] (reuses K+Q after frags read, wave-private)
//   MO=HB+0    : mid bf16 [64 tok][32 d] (reuses P rows 0..31 after P frags read)
__global__ __launch_bounds__(256, 3)
void win_attn_kernel(const float* __restrict__ x,
                     const float* __restrict__ mask,
                     const float* __restrict__ proj_b,
                     const char*  __restrict__ ws,
                     float* __restrict__ out) {
  __shared__ __align__(16) char smem[49152];
  const int b    = blockIdx.x;
  const int tid  = threadIdx.x;
  const int w    = tid >> 6;        // wave id == head id
  const int lane = tid & 63;
  const int l16  = lane & 15;
  const int lg   = lane >> 4;

  const unsigned short* qkvT  = (const unsigned short*)(ws + OFF_QKVT);
  const unsigned short* projT = (const unsigned short*)(ws + OFF_PROJT);
  const float* biasF = (const float*)(ws + OFF_BIAS);
  const float* bsc   = (const float*)(ws + OFF_BSC);

  const unsigned HB = (unsigned)w * 12288u;
  const unsigned KO = HB, QO = HB + 4096u, VT = HB + 8192u;
  const unsigned rsw = ((unsigned)((l16 >> 2) & 3)) << 4;  // row-swizzle for 64B-row tiles

  // ================= GEMM1: wave w computes q,k,v of head w ==================
  // n-tiles t: 0,1 -> q cols 32w+16t ; 2,3 -> k ; 4,5 -> v
  f32x4 acc[6][4];
  int colb[6];
#pragma unroll
  for (int t = 0; t < 6; ++t) {
    colb[t] = (t < 2) ? (32*w + 16*t)
            : (t < 4) ? (128 + 32*w + 16*(t-2))
                      : (256 + 32*w + 16*(t-4));
    float bi = bsc[colb[t] + l16];
#pragma unroll
    for (int mt = 0; mt < 4; ++mt) acc[t][mt] = (f32x4){bi, bi, bi, bi};
  }
  const float* xb = x + (size_t)b * 6272;
#pragma unroll
  for (int ks = 0; ks < 4; ++ks) {
    bf16x8 a[4];
#pragma unroll
    for (int mt = 0; mt < 4; ++mt) {
      int tok = 16*mt + l16;
      int tc  = tok > 48 ? 48 : tok;            // rows >=49: harmless clamp (masked later)
      const float* xp = xb + tc*128 + 32*ks + 8*lg;
      float4 v0 = *(const float4*)xp;
      float4 v1 = *(const float4*)(xp + 4);
      union { u32x4 u; bf16x8 h; } pk;
      pk.u.x = pk2(v0.x, v0.y); pk.u.y = pk2(v0.z, v0.w);
      pk.u.z = pk2(v1.x, v1.y); pk.u.w = pk2(v1.z, v1.w);
      a[mt] = pk.h;
    }
#pragma unroll
    for (int t = 0; t < 6; ++t) {
      bf16x8 bf = *(const bf16x8*)(qkvT + (size_t)(colb[t] + l16) * 128 + 32*ks + 8*lg);
#pragma unroll
      for (int mt = 0; mt < 4; ++mt) acc[t][mt] = MFMA16(a[mt], bf, acc[t][mt]);
    }
  }

  // epilogue: q,k scalar b16 (row-major [tok][d]); v packed b64 into Vt (wave-private)
#pragma unroll
  for (int t = 0; t < 4; ++t) {
    unsigned base = (t < 2) ? QO : KO;
    int dl = (t & 1) * 16 + l16;
#pragma unroll
    for (int mt = 0; mt < 4; ++mt)
#pragma unroll
      for (int i = 0; i < 4; ++i) {
        int tok = 16*mt + 4*lg + i;              // (tok>>2)&3 == lg
        unsigned byte = base + (unsigned)tok * 64u +
                        (((unsigned)(dl * 2)) ^ ((unsigned)lg << 4));
        *(unsigned short*)(smem + byte) = bf1(acc[t][mt][i]);
      }
  }
#pragma unroll
  for (int t = 4; t < 6; ++t) {
    int d = (t & 1) * 16 + l16;
    unsigned rowb = VT + (unsigned)d * 128u;
    unsigned sw   = ((unsigned)(d & 7)) << 4;
#pragma unroll
    for (int mt = 0; mt < 4; ++mt) {
      unsigned byte = rowb + (((unsigned)(32*mt + 8*lg)) ^ sw);
      *(uint2*)(smem + byte) = make_uint2(pk2(acc[t][mt][0], acc[t][mt][1]),
                                          pk2(acc[t][mt][2], acc[t][mt][3]));
    }
  }

  // ================= QK^T swapped: S^T[key][q] = mfma(K, Q) =================
  bf16x8 kf[4], qf[4];
#pragma unroll
  for (int kt = 0; kt < 4; ++kt)
    kf[kt] = *(const bf16x8*)(smem + KO + (unsigned)(16*kt + l16) * 64u +
                              (((unsigned)(16*lg)) ^ rsw));
#pragma unroll
  for (int qt = 0; qt < 4; ++qt)
    qf[qt] = *(const bf16x8*)(smem + QO + (unsigned)(16*qt + l16) * 64u +
                              (((unsigned)(16*lg)) ^ rsw));
  f32x4 p[4][4];  // [kt][qt]: row=key=16kt+4lg+i, col=q=16qt+l16
#pragma unroll
  for (int kt = 0; kt < 4; ++kt)
#pragma unroll
    for (int qt = 0; qt < 4; ++qt) p[kt][qt] = (f32x4){0.f, 0.f, 0.f, 0.f};
#pragma unroll
  for (int kt = 0; kt < 4; ++kt)
#pragma unroll
    for (int qt = 0; qt < 4; ++qt) p[kt][qt] = MFMA16(kf[kt], qf[qt], p[kt][qt]);

  // bias + mask + bounds, then row-softmax (q is lane-local: 16 in-lane + 2 shfl)
  const float* mb = mask + (size_t)b * 2401;
  const float* bh = biasF + w * 2401;
  float rs[4];
#pragma unroll
  for (int qt = 0; qt < 4; ++qt) {
    int q = 16*qt + l16;
#pragma unroll
    for (int kt = 0; kt < 4; ++kt)
#pragma unroll
      for (int i = 0; i < 4; ++i) {
        int key = 16*kt + 4*lg + i;
        float v = p[kt][qt][i];
        if (q < 49 && key < 49) v += bh[q*49 + key] + mb[q*49 + key];
        else v = -1e30f;
        p[kt][qt][i] = v;
      }
    float m = -1e30f;
#pragma unroll
    for (int kt = 0; kt < 4; ++kt)
#pragma unroll
      for (int i = 0; i < 4; ++i) m = fmaxf(m, p[kt][qt][i]);
    m = fmaxf(m, __shfl_xor(m, 16));
    m = fmaxf(m, __shfl_xor(m, 32));
    float s = 0.f;
#pragma unroll
    for (int kt = 0; kt < 4; ++kt)
#pragma unroll
      for (int i = 0; i < 4; ++i) {
        float e = __expf(p[kt][qt][i] - m);
        p[kt][qt][i] = e;
        s += e;
      }
    s += __shfl_xor(s, 16);
    s += __shfl_xor(s, 32);
    rs[qt] = 1.0f / s;
  }

  // P -> bf16, packed b64 into PO (row-major [q][key], reuses K+Q; wave-private)
#pragma unroll
  for (int qt = 0; qt < 4; ++qt) {
    int q = 16*qt + l16;
    unsigned rowb = HB + (unsigned)q * 128u;
    unsigned sw   = ((unsigned)(q & 7)) << 4;
#pragma unroll
    for (int kt = 0; kt < 4; ++kt) {
      unsigned byte = rowb + (((unsigned)(32*kt + 8*lg)) ^ sw);
      *(uint2*)(smem + byte) = make_uint2(pk2(p[kt][qt][0], p[kt][qt][1]),
                                          pk2(p[kt][qt][2], p[kt][qt][3]));
    }
  }

  // ================= PV swapped: O^T[d][q] = mfma(Vt, P) =================
  bf16x8 af[2][2], pb[4][2];
#pragma unroll
  for (int dt = 0; dt < 2; ++dt)
#pragma unroll
    for (int ks = 0; ks < 2; ++ks)
      af[dt][ks] = *(const bf16x8*)(smem + VT + (unsigned)(16*dt + l16) * 128u +
                                    (((unsigned)(64*ks + 16*lg)) ^ (((unsigned)(l16 & 7)) << 4)));
#pragma unroll
  for (int qt = 0; qt < 4; ++qt)
#pragma unroll
    for (int ks = 0; ks < 2; ++ks)
      pb[qt][ks] = *(const bf16x8*)(smem + HB + (unsigned)(16*qt + l16) * 128u +
                                    (((unsigned)(64*ks + 16*lg)) ^ (((unsigned)(l16 & 7)) << 4)));
  f32x4 o[2][4];
#pragma unroll
  for (int dt = 0; dt < 2; ++dt)
#pragma unroll
    for (int qt = 0; qt < 4; ++qt) o[dt][qt] = (f32x4){0.f, 0.f, 0.f, 0.f};
#pragma unroll
  for (int ks = 0; ks < 2; ++ks)
#pragma unroll
    for (int dt = 0; dt < 2; ++dt)
#pragma unroll
      for (int qt = 0; qt < 4; ++qt)
        o[dt][qt] = MFMA16(af[dt][ks], pb[qt][ks], o[dt][qt]);

  // normalize + write mid (row-major [q][32 d] at MO, packed b64; wave-private)
#pragma unroll
  for (int qt = 0; qt < 4; ++qt) {
    int q = 16*qt + l16;
    unsigned rowb = HB + (unsigned)q * 64u;
#pragma unroll
    for (int dt = 0; dt < 2; ++dt) {
      float m0 = o[dt][qt][0] * rs[qt], m1 = o[dt][qt][1] * rs[qt];
      float m2 = o[dt][qt][2] * rs[qt], m3 = o[dt][qt][3] * rs[qt];
      unsigned byte = rowb + (((unsigned)(32*dt + 8*lg)) ^ rsw);
      *(uint2*)(smem + byte) = make_uint2(pk2(m0, m1), pk2(m2, m3));
    }
  }

  __syncthreads();  // the only barrier: all heads' mid ready for proj GEMM

  // ================= GEMM2: out[64x128] = mid[64x128] @ projW + b =================
  // wave w owns out cols [32w, 32w+32); k-step ks == head region ks.
  f32x4 c2[2][4];
#pragma unroll
  for (int nt = 0; nt < 2; ++nt) {
    float pbv = proj_b[32*w + 16*nt + l16];
#pragma unroll
    for (int mt = 0; mt < 4; ++mt) c2[nt][mt] = (f32x4){pbv, pbv, pbv, pbv};
  }
#pragma unroll
  for (int ks = 0; ks < 4; ++ks) {
    bf16x8 a2[4];
#pragma unroll
    for (int mt = 0; mt < 4; ++mt)
      a2[mt] = *(const bf16x8*)(smem + (unsigned)ks * 12288u + (unsigned)(16*mt + l16) * 64u +
                                (((unsigned)(16*lg)) ^ rsw));
#pragma unroll
    for (int nt = 0; nt < 2; ++nt) {
      bf16x8 b2 = *(const bf16x8*)(projT + (size_t)(32*w + 16*nt + l16) * 128 + 32*ks + 8*lg);
#pragma unroll
      for (int mt = 0; mt < 4; ++mt) c2[nt][mt] = MFMA16(a2[mt], b2, c2[nt][mt]);
    }
  }
  float* ob = out + (size_t)b * 6272;
#pragma unroll
  for (int mt = 0; mt < 4; ++mt)
#pragma unroll
    for (int nt = 0; nt < 2; ++nt)
#pragma unroll
      for (int i = 0; i < 4; ++i) {
        int r = 16*mt + 4*lg + i;
        if (r < 49) ob[r * 128 + 32*w + 16*nt + l16] = c2[nt][mt][i];
      }
}

extern "C" void kernel_launch(void* const* d_in, const int* in_sizes, int n_in,
                              void* d_out, int out_size, void* d_ws, size_t ws_size,
                              hipStream_t stream) {
  const float* x          = (const float*)d_in[0];
  const float* mask       = (const float*)d_in[1];
  const float* qkv_w      = (const float*)d_in[2];
  const float* qkv_b      = (const float*)d_in[3];
  const float* proj_w     = (const float*)d_in[4];
  const float* proj_b     = (const float*)d_in[5];
  const float* bias_table = (const float*)d_in[6];
  const int*   rel_index  = (const int*)d_in[7];
  char* ws = (char*)d_ws;

  prep_kernel<<<296, 256, 0, stream>>>(qkv_w, qkv_b, proj_w, bias_table, rel_index, ws);
  win_attn_kernel<<<4096, 256, 0, stream>>>(x, mask, proj_b, ws, (float*)d_out);
}